// Round 10
// baseline (291.325 us; speedup 1.0000x reference)
//
#include <hip/hip_runtime.h>
#include <hip/hip_fp16.h>

constexpr int HID = 128;
constexpr int DH  = 64;

typedef _Float16 f16x2 __attribute__((ext_vector_type(2)));
typedef _Float16 fh4   __attribute__((ext_vector_type(4)));   // 8B packed store
typedef _Float16 fh8   __attribute__((ext_vector_type(8)));   // 4 VGPRs, MFMA A/B frag
typedef float    f32x4v __attribute__((ext_vector_type(4)));  // MFMA C/D frag

__device__ __forceinline__ fh8 relu8(fh8 x) {
  fh8 z = {0, 0, 0, 0, 0, 0, 0, 0};
#if __has_builtin(__builtin_elementwise_max)
  return __builtin_elementwise_max(x, z);
#else
  fh8 r;
#pragma unroll
  for (int i = 0; i < 8; i++) r[i] = x[i] > z[i] ? x[i] : z[i];
  return r;
#endif
}

// ---------------- merged: degree count + h->fp16 + W1 fragment table build ----------------
// fragTab[rel][g][s][l][j] = W1_rel[krow][jslot], k = s*32+(l>>4)*8+j, jslot=(g&7)*16+(l&15)
// g<8: u part (krow=k); g>=8: v part (krow=F+k). Zero-padded where k>=F.
// Used as the A-operand in uv_mfma (A-frag row=lane&15 == B-frag col=lane&15: same table).
__global__ void count_h16_frag_kernel(const int* __restrict__ dst, int* __restrict__ counts, int E,
                                      const float* __restrict__ h, _Float16* __restrict__ h16, int total,
                                      const float* __restrict__ w1a, const float* __restrict__ w1b,
                                      _Float16* __restrict__ fragTab) {
  int i = blockIdx.x * 256 + threadIdx.x;
  if (blockIdx.x < 128) {
    int flat = i;
    int rel = flat >> 14;
    int r2 = flat & 16383;
    int g = r2 >> 10, s = (r2 >> 9) & 1, l = (r2 >> 3) & 63, j = r2 & 7;
    int bc = l & 15, bkg = l >> 4;
    int k = s * 32 + bkg * 8 + j;
    int F = rel ? 32 : 64;
    const float* w1 = rel ? w1b : w1a;
    float val = 0.f;
    if (k < F) {
      int jslot = (g & 7) * 16 + bc;
      int krow = (g < 8) ? k : (F + k);
      val = w1[krow * HID + jslot];
    }
    fragTab[flat] = (_Float16)val;
  }
  if (i < E) atomicAdd(&counts[dst[i]], 1);
  int base = i * 8;
  if (base + 7 < total) {
    float4 f0 = *(const float4*)(h + base);
    float4 f1 = *(const float4*)(h + base + 4);
    fh8 t;
    t[0] = (_Float16)f0.x; t[1] = (_Float16)f0.y; t[2] = (_Float16)f0.z; t[3] = (_Float16)f0.w;
    t[4] = (_Float16)f1.x; t[5] = (_Float16)f1.y; t[6] = (_Float16)f1.z; t[7] = (_Float16)f1.w;
    *(fh8*)(h16 + base) = t;
  }
}

// ---------------- uv precompute via MFMA, transposed: D = W1T_block . featT ----------------
// C cols = 16 nodes, rows = feature j  ->  the 4 q-values per lane are CONSECUTIVE u_cat
// addresses: one packed 8B store per tile instead of 4 scattered 2B stores (round-9: 64
// scattered st/lane). fragTab unchanged (A-frag lane mapping == old B-frag mapping).
__launch_bounds__(256)
__global__ void uv_mfma_kernel(const float* __restrict__ pca, const float* __restrict__ pimg,
                               const float* __restrict__ b1a, const float* __restrict__ b1b,
                               const _Float16* __restrict__ fragTab,
                               _Float16* __restrict__ u_cat, _Float16* __restrict__ v_cat, int N) {
  __shared__ _Float16 sB[16384];   // [g(16)][s(2)][l(64)][j(8)]
  int rel = blockIdx.y;
  const float* feat = rel ? pimg : pca;
  const float* b1   = rel ? b1b : b1a;
  int F  = rel ? 32 : 64;
  int KS = rel ? 1 : 2;
  int tid = threadIdx.x;
  {  // linear coalesced copy of this relation's frag table
    const fh8* srcp = (const fh8*)(fragTab + rel * 16384);
    fh8* dstp = (fh8*)sB;
    for (int i = tid; i < 2048; i += 256) dstp[i] = srcp[i];
  }
  __syncthreads();
  int lane = tid & 63, w = tid >> 6;
  int c = lane & 15, kg = lane >> 4;
  int node = blockIdx.x * 64 + w * 16 + c;          // B-fragment: col = node
  int nclamp = node < N ? node : N - 1;
  fh8 bfeat[2];
#pragma unroll
  for (int s = 0; s < 2; s++) {
    if (s < KS) {
      const float* fp = feat + (size_t)nclamp * F + s * 32 + kg * 8;
      float4 f0 = *(const float4*)fp;
      float4 f1 = *(const float4*)(fp + 4);
      fh8 t;
      t[0] = (_Float16)f0.x; t[1] = (_Float16)f0.y; t[2] = (_Float16)f0.z; t[3] = (_Float16)f0.w;
      t[4] = (_Float16)f1.x; t[5] = (_Float16)f1.y; t[6] = (_Float16)f1.z; t[7] = (_Float16)f1.w;
      bfeat[s] = t;
    }
  }
  // per-lane v-bias values for rows kg*4..kg*4+3 of each 16-j block
  float4 b1q[8];
#pragma unroll
  for (int g = 0; g < 8; g++) b1q[g] = *(const float4*)(b1 + g * 16 + kg * 4);

  bool wr = node < N;
#pragma unroll
  for (int g = 0; g < 16; g++) {
    f32x4v acc = {0.f, 0.f, 0.f, 0.f};
    acc = __builtin_amdgcn_mfma_f32_16x16x32_f16(((const fh8*)sB)[(g * 2 + 0) * 64 + lane], bfeat[0], acc, 0, 0, 0);
    if (KS == 2)
      acc = __builtin_amdgcn_mfma_f32_16x16x32_f16(((const fh8*)sB)[(g * 2 + 1) * 64 + lane], bfeat[1], acc, 0, 0, 0);
    bool isv = g >= 8;
    int jbase = (g & 7) * 16 + kg * 4;              // C rows: j = jbase + q
    float4 bias = isv ? b1q[g & 7] : make_float4(0.f, 0.f, 0.f, 0.f);
    fh4 pk;
    pk[0] = (_Float16)(acc[0] + bias.x);
    pk[1] = (_Float16)(acc[1] + bias.y);
    pk[2] = (_Float16)(acc[2] + bias.z);
    pk[3] = (_Float16)(acc[3] + bias.w);
    _Float16* outp = isv ? v_cat : u_cat;
    if (wr) *(fh4*)(outp + (size_t)node * 256 + rel * 128 + jbase) = pk;
  }
}

// ---------------- CSR scans ----------------
__launch_bounds__(256)
__global__ void scan1_kernel(const int* __restrict__ counts, int* __restrict__ bsums, int N) {
  int b = blockIdx.x, tid = threadIdx.x;
  int base = b * 1024 + tid * 4;
  int s = 0;
  if (base + 3 < N) {
    int4 v = *(const int4*)(counts + base);
    s = v.x + v.y + v.z + v.w;
  } else {
    for (int q = 0; q < 4; q++) { int idx = base + q; if (idx < N) s += counts[idx]; }
  }
#pragma unroll
  for (int o = 32; o >= 1; o >>= 1) s += __shfl_xor(s, o);
  __shared__ int ws[4];
  if ((tid & 63) == 0) ws[tid >> 6] = s;
  __syncthreads();
  if (tid == 0) bsums[b] = ws[0] + ws[1] + ws[2] + ws[3];
}

__launch_bounds__(1024)
__global__ void scan2_kernel(const int* __restrict__ bsums, int* __restrict__ bpre,
                             int* __restrict__ offsets, int NB, int N, int E) {
  int tid = threadIdx.x, lane = tid & 63, w = tid >> 6;
  int v = (tid < NB) ? bsums[tid] : 0;
  int incl = v;
#pragma unroll
  for (int o = 1; o < 64; o <<= 1) { int t = __shfl_up(incl, o); if (lane >= o) incl += t; }
  __shared__ int ws[16];
  if (lane == 63) ws[w] = incl;
  __syncthreads();
  int wpre = 0;
  for (int q = 0; q < w; q++) wpre += ws[q];
  if (tid < NB) bpre[tid] = wpre + incl - v;
  if (tid == 0) offsets[N] = E;
}

__launch_bounds__(256)
__global__ void scan3_kernel(const int* __restrict__ counts, const int* __restrict__ bpre,
                             int* __restrict__ offsets, int N) {
  int b = blockIdx.x, tid = threadIdx.x, lane = tid & 63, w = tid >> 6;
  int base = b * 1024 + tid * 4;
  int c[4] = {0, 0, 0, 0};
  if (base + 3 < N) {
    int4 v = *(const int4*)(counts + base);
    c[0] = v.x; c[1] = v.y; c[2] = v.z; c[3] = v.w;
  } else {
    for (int q = 0; q < 4; q++) { int idx = base + q; if (idx < N) c[q] = counts[idx]; }
  }
  int s = c[0] + c[1] + c[2] + c[3];
  int incl = s;
#pragma unroll
  for (int o = 1; o < 64; o <<= 1) { int t = __shfl_up(incl, o); if (lane >= o) incl += t; }
  int excl = incl - s;
  __shared__ int ws[4];
  if (lane == 63) ws[w] = incl;
  __syncthreads();
  int wpre = 0;
  for (int q = 0; q < w; q++) wpre += ws[q];
  int off = bpre[b] + wpre + excl;
  for (int q = 0; q < 4; q++) {
    int idx = base + q;
    if (idx < N) offsets[idx] = off;
    off += c[q];
  }
}

// cursor pre-seeded with offsets (d2d memcpy) -> single atomic, no offsets read
__global__ void fill_kernel(const int* __restrict__ src, const int* __restrict__ dst,
                            int* __restrict__ cursor, int2* __restrict__ edges, int E) {
  int e = blockIdx.x * 256 + threadIdx.x;
  if (e < E) {
    int d = dst[e];
    int pos = atomicAdd(&cursor[d], 1);
    edges[pos] = make_int2(src[e], d);
  }
}

// ---------------- MFMA per-edge scores -> ek = exp(leaky_relu(mlp)), fp16 ----------------
// At the measured random-gather wall (205MB L2-miss @ ~2.55 TB/s, 3 rounds stable) — frozen.
__launch_bounds__(256, 8)
__global__ void score_kernel(const _Float16* __restrict__ u_cat, const _Float16* __restrict__ v_cat,
                             const int2* __restrict__ edges,
                             const float* __restrict__ w2a, const float* __restrict__ w2b,
                             const float* __restrict__ b2a, const float* __restrict__ b2b,
                             _Float16* __restrict__ ek, int E) {
  __shared__ _Float16 sB[8 * 64 * 8];   // [t][lane][j] B-fragments of W2cat (block-diag)
  int tid = threadIdx.x, lane = tid & 63, w = tid >> 6;
  int col = lane & 15, kg = lane >> 4;
  for (int idx = tid; idx < 4096; idx += 256) {
    int t = idx >> 9, l = (idx >> 3) & 63, j = idx & 7;
    int bc = l & 15;
    int k = t * 32 + ((l >> 4) << 3) + j;
    float val = 0.f;
    if (bc < 4) { if (k < 128) val = w2a[k * 4 + bc]; }
    else if (bc < 8) { if (k >= 128) val = w2b[(k - 128) * 4 + (bc - 4)]; }
    sB[idx] = (_Float16)val;
  }
  __syncthreads();

  int ebase = blockIdx.x * 256 + w * 64;
  const _Float16* up[4];
  const _Float16* vp[4];
#pragma unroll
  for (int m = 0; m < 4; m++) {
    int em = ebase + m * 16 + col;
    int ec = em < E ? em : 0;          // clamp; epilogue guards stores
    int2 sd = edges[ec];
    up[m] = u_cat + (size_t)sd.x * 256 + kg * 8;
    vp[m] = v_cat + (size_t)sd.y * 256 + kg * 8;
  }

  f32x4v acc[4];
#pragma unroll
  for (int m = 0; m < 4; m++) acc[m] = (f32x4v){0.f, 0.f, 0.f, 0.f};

#pragma unroll
  for (int t = 0; t < 8; t++) {
    fh8 bf = *(const fh8*)(sB + ((t * 64 + lane) << 3));
#pragma unroll
    for (int m = 0; m < 4; m++) {
      fh8 uu = *(const fh8*)(up[m] + t * 32);
      fh8 vv = *(const fh8*)(vp[m] + t * 32);
      acc[m] = __builtin_amdgcn_mfma_f32_16x16x32_f16(relu8(uu + vv), bf, acc[m], 0, 0, 0);
    }
  }

  if (col < 8) {
    float b2v = (col < 4) ? b2a[col] : b2b[col - 4];
#pragma unroll
    for (int m = 0; m < 4; m++) {
#pragma unroll
      for (int q = 0; q < 4; q++) {
        int er = ebase + m * 16 + kg * 4 + q;
        if (er < E) {
          float x = acc[m][q] + b2v;
          x = x > 0.f ? x : 0.01f * x;
          ek[(size_t)er * 8 + col] = (_Float16)__expf(x);
        }
      }
    }
  }
}

// ---------------- softmax-normalize + aggregate: one wave per dst node, ONE pass ----------------
// Lane-halves process even/odd edges, 2 channels/lane: one VMEM fetches TWO h-rows
// (64 lanes x 4B = 2 x 128B), VMEM issues 9 -> 6 per 4 edges, 2 independent gather chains.
// Cross-half combine at the end (24 shuffles), heads split across halves for the store.
__launch_bounds__(256, 8)
__global__ void agg_kernel(const _Float16* __restrict__ ek, const int2* __restrict__ edges,
                           const int* __restrict__ offsets, const _Float16* __restrict__ h16,
                           float* __restrict__ out, int N) {
  int wid = blockIdx.x * 4 + (threadIdx.x >> 6);
  int lane = threadIdx.x & 63;
  if (wid >= N) return;
  int off0 = offsets[wid], off1 = offsets[wid + 1];
  int deg = off1 - off0;
  float* op = out + (size_t)wid * 512;
  if (deg == 0) {
#pragma unroll
    for (int k = 0; k < 4; k++) { op[k * 128 + lane] = 0.f; op[k * 128 + 64 + lane] = 0.f; }
    return;
  }
  int half = lane >> 5, lq = lane & 31;
  float2 accO[8];
  float ssum[8];
#pragma unroll
  for (int k = 0; k < 8; k++) { accO[k] = make_float2(0.f, 0.f); ssum[k] = 0.f; }
  int last = off1 - 1;
  for (int jj = 0; jj < deg; jj += 4) {
    int iA = off0 + jj + half;
    int iB = off0 + jj + 2 + half;
    bool mA = jj + half < deg, mB = jj + 2 + half < deg;
    iA = min(iA, last); iB = min(iB, last);
    int sA = edges[iA].x, sB2 = edges[iB].x;
    fh8 eA = *(const fh8*)(ek + (size_t)iA * 8);
    fh8 eB = *(const fh8*)(ek + (size_t)iB * 8);
    f16x2 hA = *(const f16x2*)(h16 + (size_t)sA * DH + lq * 2);
    f16x2 hB = *(const f16x2*)(h16 + (size_t)sB2 * DH + lq * 2);
    float hA0 = (float)hA[0], hA1 = (float)hA[1];
    float hB0 = (float)hB[0], hB1 = (float)hB[1];
#pragma unroll
    for (int k = 0; k < 8; k++) {
      float ea = mA ? (float)eA[k] : 0.f;
      float eb = mB ? (float)eB[k] : 0.f;
      accO[k].x = fmaf(ea, hA0, accO[k].x);
      accO[k].x = fmaf(eb, hB0, accO[k].x);
      accO[k].y = fmaf(ea, hA1, accO[k].y);
      accO[k].y = fmaf(eb, hB1, accO[k].y);
      ssum[k] += ea + eb;
    }
  }
#pragma unroll
  for (int k = 0; k < 8; k++) {
    accO[k].x += __shfl_xor(accO[k].x, 32);
    accO[k].y += __shfl_xor(accO[k].y, 32);
    ssum[k]   += __shfl_xor(ssum[k], 32);
  }
  // half 0 stores heads 0..3 (pca cols), half 1 stores heads 4..7 (pimg cols)
#pragma unroll
  for (int t = 0; t < 4; t++) {
    int k = half * 4 + t;
    float rsv = 1.f / ssum[k];
    int colbase = (k < 4) ? (k * 128 + lq * 2) : ((k - 4) * 128 + 64 + lq * 2);
    float2 v2 = make_float2(accO[k].x * rsv, accO[k].y * rsv);
    *(float2*)(op + colbase) = v2;
  }
}

extern "C" void kernel_launch(void* const* d_in, const int* in_sizes, int n_in,
                              void* d_out, int out_size, void* d_ws, size_t ws_size,
                              hipStream_t stream) {
  const float* h      = (const float*)d_in[0];
  const float* pca    = (const float*)d_in[1];
  const float* pimg   = (const float*)d_in[2];
  const float* pca_w1 = (const float*)d_in[3];
  const float* pca_b1 = (const float*)d_in[4];
  const float* pca_w2 = (const float*)d_in[5];
  const float* pca_b2 = (const float*)d_in[6];
  const float* pi_w1  = (const float*)d_in[7];
  const float* pi_b1  = (const float*)d_in[8];
  const float* pi_w2  = (const float*)d_in[9];
  const float* pi_b2  = (const float*)d_in[10];
  const int*   src    = (const int*)d_in[11];
  const int*   dst    = (const int*)d_in[12];
  int N = in_sizes[0] / 64;
  int E = in_sizes[11];
  float* out = (float*)d_out;

  char* ws = (char*)d_ws;
  size_t o = 0;
  auto alloc = [&](size_t bytes) { void* p = ws + o; o += (bytes + 255) & ~(size_t)255; return p; };
  _Float16* u_cat  = (_Float16*)alloc((size_t)N * 256 * 2);
  _Float16* v_cat  = (_Float16*)alloc((size_t)N * 256 * 2);
  _Float16* h16    = (_Float16*)alloc((size_t)N * 64 * 2);
  _Float16* fragTab = (_Float16*)alloc(32768 * 2);
  int* counts  = (int*)alloc((size_t)N * 4);
  int* cursor  = (int*)alloc((size_t)N * 4);
  int* offsets = (int*)alloc((size_t)(N + 1) * 4);
  int* bsums   = (int*)alloc(1024 * 4);
  int* bpre    = (int*)alloc(1024 * 4);
  int2* edges  = (int2*)alloc((size_t)E * 8);
  _Float16* ekb = (_Float16*)alloc((size_t)E * 8 * 2);

  hipMemsetAsync(counts, 0, (size_t)N * 4, stream);

  count_h16_frag_kernel<<<(E + 255) / 256, 256, 0, stream>>>(dst, counts, E, h, h16, N * 64,
                                                             pca_w1, pi_w1, fragTab);
  dim3 uvgrid((N + 63) / 64, 2);
  uv_mfma_kernel<<<uvgrid, 256, 0, stream>>>(pca, pimg, pca_b1, pi_b1, fragTab, u_cat, v_cat, N);
  int NB = (N + 1023) / 1024;
  scan1_kernel<<<NB, 256, 0, stream>>>(counts, bsums, N);
  scan2_kernel<<<1, 1024, 0, stream>>>(bsums, bpre, offsets, NB, N, E);
  scan3_kernel<<<NB, 256, 0, stream>>>(counts, bpre, offsets, N);
  hipMemcpyAsync(cursor, offsets, (size_t)N * 4, hipMemcpyDeviceToDevice, stream);
  fill_kernel<<<(E + 255) / 256, 256, 0, stream>>>(src, dst, cursor, edges, E);
  score_kernel<<<(E + 255) / 256, 256, 0, stream>>>(u_cat, v_cat, edges,
                                                    pca_w2, pi_w2, pca_b2, pi_b2, ekb, E);
  agg_kernel<<<(N + 3) / 4, 256, 0, stream>>>(ekb, edges, offsets, h16, out, N);
}